// Round 9
// baseline (625.419 us; speedup 1.0000x reference)
//
#include <hip/hip_runtime.h>
#include <cmath>

// x [B=4096][T=512][D=4], H=32, gates 4H=128 (PyTorch order i,f,g,o).
constexpr int T   = 512;
constexpr int D   = 4;
constexpr int H   = 32;
constexpr int BT  = 8;     // real batch cols per block; MFMA cols 8-15 mirror cols 0-7
constexpr int BLK = 256;   // 4 waves: (layer, unit-half)

typedef short bf8 __attribute__((ext_vector_type(8)));  // 8 bf16 (4 VGPRs)
typedef short s4v __attribute__((ext_vector_type(4)));  // 4 bf16 (8B)
typedef float f4  __attribute__((ext_vector_type(4)));  // MFMA C/D

static __device__ __forceinline__ float sigm(float z) {
    return __builtin_amdgcn_rcpf(1.0f + __expf(-z));
}
static __device__ __forceinline__ float tanh_f(float z) {
    return fmaf(__builtin_amdgcn_rcpf(1.0f + __expf(-2.0f * z)), 2.0f, -1.0f);
}
// fp32 -> bf16 hi (truncate) + bf16 lo (residual): hi+lo ~ 16 mantissa bits
static __device__ __forceinline__ void splitf(float v, short& hi, short& lo) {
    unsigned uv = __float_as_uint(v);
    hi = (short)(uv >> 16);
    float r = v - __uint_as_float(uv & 0xffff0000u);
    lo = (short)(__float_as_uint(r) >> 16);
}

// Wave w = (layer = w>>1, ug = (w&1)*16). The wave computes, for its 16
// units, ALL FOUR gate tiles (tile g covers gate rows 32g+ug..32g+ug+15),
// so after the MFMAs each lane holds i,f,g,o of units ug+4q+r for col nl
// IN REGISTERS -> the state update is lane-local, zero gate LDS traffic
// (R8's DS-pipe bottleneck). h round-trips LDS only as pre-split bf16
// fragments, double-buffered -> ONE barrier per iter. Cols 8-15 mirror
// cols 0-7 exactly (same x stream, zero-init h) — bounded junk, never read.
__global__ __launch_bounds__(BLK, 2) void lstm_lane(
    const float* __restrict__ x,
    const float* __restrict__ W_ih0, const float* __restrict__ W_hh0,
    const float* __restrict__ b_ih0, const float* __restrict__ b_hh0,
    const float* __restrict__ W_ih1, const float* __restrict__ W_hh1,
    const float* __restrict__ b_ih1, const float* __restrict__ b_hh1,
    const float* __restrict__ W_out, const float* __restrict__ b_out,
    float* __restrict__ out)
{
    // [buf][col][unit], row stride 56 shorts (112 B: b128-aligned at 8q offsets)
    __shared__ __align__(16) short h0hi[2][16][56];
    __shared__ __align__(16) short h0lo[2][16][56];
    __shared__ __align__(16) short h1hi[2][16][56];
    __shared__ __align__(16) short h1lo[2][16][56];
    __shared__ __align__(16) float h1f[BT][36];     // final h1 fp32 for the head

    const int tid   = threadIdx.x;
    const int w     = tid >> 6;
    const int lane  = tid & 63;
    const int q     = lane >> 4;
    const int nl    = lane & 15;
    const int nc    = nl & 7;          // real batch col (nl>=8 mirrors)
    const int layer = w >> 1;          // 0: L1, 1: L2
    const int ug    = (w & 1) << 4;    // unit group offset 0 / 16
    const int b0    = blockIdx.x * BT;

    // zero both h buffers (junk cols too — mirror induction base)
    for (int idx = tid; idx < 2 * 16 * 56; idx += BLK) {
        (&h0hi[0][0][0])[idx] = 0; (&h0lo[0][0][0])[idx] = 0;
        (&h1hi[0][0][0])[idx] = 0; (&h1lo[0][0][0])[idx] = 0;
    }

    // ---- weights: tile g = gate type. A-frag row = 32g + ug + nl, k = 8q+j.
    // W1 dotted with h0 (L1: W_hh0, L2: W_ih1); W2 with the second operand
    // (L1: W_ih0 vs x, K-padded; L2: W_hh1 vs h1).
    const float* W1 = layer ? W_ih1 : W_hh0;
    bf8 w1h[4], w1l[4], w2h[4], w2l[4];
    f4  bias[4];
    #pragma unroll
    for (int g = 0; g < 4; ++g) {
        const int row = 32 * g + ug + nl;
        #pragma unroll
        for (int j = 0; j < 8; ++j) {
            short a, b;
            splitf(W1[row * H + 8 * q + j], a, b); w1h[g][j] = a; w1l[g][j] = b;
            float v2 = layer ? W_hh1[row * H + 8 * q + j]
                             : ((q == 0 && j < 4) ? W_ih0[row * D + j] : 0.0f);
            splitf(v2, a, b); w2h[g][j] = a; w2l[g][j] = b;
        }
        #pragma unroll
        for (int r = 0; r < 4; ++r) {
            const int gr = 32 * g + ug + 4 * q + r;
            bias[g][r] = layer ? (b_ih1[gr] + b_hh1[gr]) : (b_ih0[gr] + b_hh0[gr]);
        }
    }

    const float4* xp = (const float4*)(x + (size_t)(b0 + nc) * (T * D));
    float4 xcur;
    if (layer == 0) xcur = xp[0];

    float c[4] = {0.0f, 0.0f, 0.0f, 0.0f};   // cell state of the 4 owned units

    __syncthreads();

    #pragma unroll 1
    for (int i = 0; i <= T; ++i) {
        const int rb = i & 1, wb = rb ^ 1;

        // B-fragments (ds_read_b128, 112B row stride -> conflict-free spread)
        bf8 b1h = *(const bf8*)&h0hi[rb][nl][8 * q];   // h0(i-1)
        bf8 b1l = *(const bf8*)&h0lo[rb][nl][8 * q];
        bf8 b2h, b2l;
        if (layer == 0) {   // x(i) fragment: k<4 = x, rest zero (A cols zero too)
            bf8 z = {0,0,0,0,0,0,0,0};
            b2h = z; b2l = z;
            short a, b;
            splitf(xcur.x, a, b); b2h[0] = a; b2l[0] = b;
            splitf(xcur.y, a, b); b2h[1] = a; b2l[1] = b;
            splitf(xcur.z, a, b); b2h[2] = a; b2l[2] = b;
            splitf(xcur.w, a, b); b2h[3] = a; b2l[3] = b;
            xcur = xp[(i + 1 < T) ? (i + 1) : (T - 1)];   // prefetch
        } else {            // h1(i-2) fragment
            b2h = *(const bf8*)&h1hi[rb][nl][8 * q];
            b2l = *(const bf8*)&h1lo[rb][nl][8 * q];
        }

        // ---- 24 MFMAs: 4 gate tiles x (two independent 3-chains) ----
        f4 acc[4];
        #pragma unroll
        for (int g = 0; g < 4; ++g) {
            f4 A = bias[g];
            A = __builtin_amdgcn_mfma_f32_16x16x32_bf16(w1h[g], b1h, A, 0, 0, 0);
            A = __builtin_amdgcn_mfma_f32_16x16x32_bf16(w1h[g], b1l, A, 0, 0, 0);
            A = __builtin_amdgcn_mfma_f32_16x16x32_bf16(w1l[g], b1h, A, 0, 0, 0);
            f4 R = {0.0f, 0.0f, 0.0f, 0.0f};
            R = __builtin_amdgcn_mfma_f32_16x16x32_bf16(w2h[g], b2h, R, 0, 0, 0);
            R = __builtin_amdgcn_mfma_f32_16x16x32_bf16(w2h[g], b2l, R, 0, 0, 0);
            R = __builtin_amdgcn_mfma_f32_16x16x32_bf16(w2l[g], b2h, R, 0, 0, 0);
            acc[g] = A + R;
        }

        // ---- lane-local state update: units ug+4q+r, col nl ----
        const bool act = layer ? (i >= 1) : (i < T);
        if (act) {
            s4v hh, hl;
            float hv[4];
            #pragma unroll
            for (int r = 0; r < 4; ++r) {
                float iv = sigm(acc[0][r]);
                float fv = sigm(acc[1][r]);
                float gv = tanh_f(acc[2][r]);
                float ov = sigm(acc[3][r]);
                c[r] = fmaf(fv, c[r], iv * gv);
                hv[r] = ov * tanh_f(c[r]);
                short a, b; splitf(hv[r], a, b); hh[r] = a; hl[r] = b;
            }
            if (layer == 0) {
                *(s4v*)&h0hi[wb][nl][ug + 4 * q] = hh;
                *(s4v*)&h0lo[wb][nl][ug + 4 * q] = hl;
            } else {
                *(s4v*)&h1hi[wb][nl][ug + 4 * q] = hh;
                *(s4v*)&h1lo[wb][nl][ug + 4 * q] = hl;
                if (i == T && nl < 8) {   // h1(T-1) for the output head
                    float4 hw; hw.x = hv[0]; hw.y = hv[1]; hw.z = hv[2]; hw.w = hv[3];
                    *(float4*)&h1f[nl][ug + 4 * q] = hw;
                }
            }
        }
        __syncthreads();   // single barrier: buffer wb now visible as rb of i+1
    }

    // ---- output head: out[b0+n] = b_out + W_out . h1(T-1) ----
    if (tid < BT) {
        float acc = b_out[0];
        #pragma unroll
        for (int u = 0; u < H; ++u) acc = fmaf(W_out[u], h1f[tid][u], acc);
        out[b0 + tid] = acc;
    }
}

extern "C" void kernel_launch(void* const* d_in, const int* in_sizes, int n_in,
                              void* d_out, int out_size, void* d_ws, size_t ws_size,
                              hipStream_t stream) {
    const float* x     = (const float*)d_in[0];
    const float* W_ih0 = (const float*)d_in[1];
    const float* W_hh0 = (const float*)d_in[2];
    const float* b_ih0 = (const float*)d_in[3];
    const float* b_hh0 = (const float*)d_in[4];
    const float* W_ih1 = (const float*)d_in[5];
    const float* W_hh1 = (const float*)d_in[6];
    const float* b_ih1 = (const float*)d_in[7];
    const float* b_hh1 = (const float*)d_in[8];
    const float* W_out = (const float*)d_in[9];
    const float* b_out = (const float*)d_in[10];
    float* out = (float*)d_out;

    const int B = out_size;          // 4096
    lstm_lane<<<B / BT, BLK, 0, stream>>>(x, W_ih0, W_hh0, b_ih0, b_hh0,
                                          W_ih1, W_hh1, b_ih1, b_hh1,
                                          W_out, b_out, out);
}

// Round 10
// 552.788 us; speedup vs baseline: 1.1314x; 1.1314x over previous
//
#include <hip/hip_runtime.h>
#include <cmath>

// x [B=4096][T=512][D=4], H=32, gates 4H=128 (PyTorch order i,f,g,o).
constexpr int T   = 512;
constexpr int D   = 4;
constexpr int H   = 32;
constexpr int BT  = 8;     // real batch cols per block (MFMA cols 8-15 junk, never read)
constexpr int BLK = 512;   // 8 waves: wave = (layer, gate-type), 2 M-tiles each

typedef short bf8 __attribute__((ext_vector_type(8)));  // 8 bf16 (4 VGPRs)
typedef float f4  __attribute__((ext_vector_type(4)));  // MFMA C/D

static __device__ __forceinline__ float sigm(float z) {
    return __builtin_amdgcn_rcpf(1.0f + __expf(-z));
}
static __device__ __forceinline__ float tanh_f(float z) {
    return fmaf(__builtin_amdgcn_rcpf(1.0f + __expf(-2.0f * z)), 2.0f, -1.0f);
}
// fp32 -> bf16 hi (truncate) + bf16 lo (residual): hi+lo ~ 16 mantissa bits
static __device__ __forceinline__ void splitf(float v, short& hi, short& lo) {
    unsigned uv = __float_as_uint(v);
    hi = (short)(uv >> 16);
    float r = v - __uint_as_float(uv & 0xffff0000u);
    lo = (short)(__float_as_uint(r) >> 16);
}

// Grid 512 x 512 threads = 2 blocks/CU, 4 waves/SIMD (independent barriers
// across the 2 blocks fill each other's stalls).
// Phase A: wave w = (layer=w>>2, gate=w&3) computes its 2 M-tiles
//   (rows 32*gate+16p) with 12 MFMAs (two independent split-bf16 3-chains
//   per tile), writes raw-gate f4 to g-LDS. L1 waves use x via K-padded
//   W_ih0 A-frag (B-frag k<4 = x). L2 waves consume h0(i-1), h1(i-2).
// Phase B: 512 threads = exactly the 512 real (layer,unit,batch) updates
//   (1 unit/thread -> transcendental issue at its floor), h written back
//   pre-split bf16 hi/lo.
// LDS strides: g rows 136 dwords (16n+u -> ... stride%32==8 => phase-B
// gate reads exactly 2-way = free); h rows 48 shorts (96B, 2-way on b128).
__global__ __launch_bounds__(BLK, 4) void lstm_8w(
    const float* __restrict__ x,
    const float* __restrict__ W_ih0, const float* __restrict__ W_hh0,
    const float* __restrict__ b_ih0, const float* __restrict__ b_hh0,
    const float* __restrict__ W_ih1, const float* __restrict__ W_hh1,
    const float* __restrict__ b_ih1, const float* __restrict__ b_hh1,
    const float* __restrict__ W_out, const float* __restrict__ b_out,
    float* __restrict__ out)
{
    __shared__ __align__(16) float g0[16][136];   // raw L1 gates [col][row]
    __shared__ __align__(16) float g1[16][136];   // raw L2 gates
    __shared__ __align__(16) short h0hi[16][48];  // h0 split-bf16 (cols 8-15 stay 0)
    __shared__ __align__(16) short h0lo[16][48];
    __shared__ __align__(16) short h1hi[16][48];
    __shared__ __align__(16) short h1lo[16][48];
    __shared__ __align__(16) float h1f[BT][36];   // final h1 fp32 for the head

    const int tid   = threadIdx.x;
    const int w     = tid >> 6;
    const int lane  = tid & 63;
    const int q     = lane >> 4;      // quad
    const int nl    = lane & 15;      // MFMA batch col
    const int layer = w >> 2;         // 0: L1, 1: L2
    const int gate  = w & 3;          // 0:i 1:f 2:g 3:o
    const int b0    = blockIdx.x * BT;

    // zero h LDS (junk cols too; they stay 0 forever)
    for (int idx = tid; idx < 16 * 48; idx += BLK) {
        (&h0hi[0][0])[idx] = 0; (&h0lo[0][0])[idx] = 0;
        (&h1hi[0][0])[idx] = 0; (&h1lo[0][0])[idx] = 0;
    }

    // ---- weights: tile p -> A-frag row 32*gate+16p+nl, k = 8q+j ----
    // W1 dotted with h0 (L1: W_hh0, L2: W_ih1); W2 with the 2nd operand
    // (L1: W_ih0 vs x, K-padded; L2: W_hh1 vs h1).
    const float* W1 = layer ? W_ih1 : W_hh0;
    bf8 w1h[2], w1l[2], w2h[2], w2l[2];
    f4  bias[2];
    #pragma unroll
    for (int p = 0; p < 2; ++p) {
        const int row = 32 * gate + 16 * p + nl;
        #pragma unroll
        for (int j = 0; j < 8; ++j) {
            short a, b;
            splitf(W1[row * H + 8 * q + j], a, b); w1h[p][j] = a; w1l[p][j] = b;
            float v2 = layer ? W_hh1[row * H + 8 * q + j]
                             : ((q == 0 && j < 4) ? W_ih0[row * D + j] : 0.0f);
            splitf(v2, a, b); w2h[p][j] = a; w2l[p][j] = b;
        }
        #pragma unroll
        for (int r = 0; r < 4; ++r) {
            const int gr = 32 * gate + 16 * p + 4 * q + r;
            bias[p][r] = layer ? (b_ih1[gr] + b_hh1[gr]) : (b_ih0[gr] + b_hh0[gr]);
        }
    }

    // x stream for L1 waves (col nl>=8 mirrors col nl&7; outputs never read)
    const float4* xp = (const float4*)(x + (size_t)(b0 + (nl & 7)) * (T * D));
    float4 xcur;
    if (layer == 0) xcur = xp[0];

    // ---- phase-B mapping: 1 real (layer, unit, batch) per thread ----
    const int ln = tid & 7;           // batch 0..7
    const int lu = (tid >> 3) & 31;   // unit 0..31
    const int ll = tid >> 8;          // layer
    float c = 0.0f;                   // cell state of the owned unit

    __syncthreads();

    #pragma unroll 1
    for (int i = 0; i <= T; ++i) {
        // ================= phase A: MFMA raw gates =================
        bf8 b1h = *(const bf8*)&h0hi[nl][8 * q];   // h0(i-1)
        bf8 b1l = *(const bf8*)&h0lo[nl][8 * q];
        bf8 b2h, b2l;
        if (layer == 0) {   // x(i) fragment: k<4 = x (A cols k>=4 are zero)
            bf8 z = {0,0,0,0,0,0,0,0};
            b2h = z; b2l = z;
            short a, b;
            splitf(xcur.x, a, b); b2h[0] = a; b2l[0] = b;
            splitf(xcur.y, a, b); b2h[1] = a; b2l[1] = b;
            splitf(xcur.z, a, b); b2h[2] = a; b2l[2] = b;
            splitf(xcur.w, a, b); b2h[3] = a; b2l[3] = b;
            xcur = xp[(i + 1 < T) ? (i + 1) : (T - 1)];   // prefetch
        } else {            // h1(i-2) fragment
            b2h = *(const bf8*)&h1hi[nl][8 * q];
            b2l = *(const bf8*)&h1lo[nl][8 * q];
        }

        float (*gb)[136] = layer ? g1 : g0;
        #pragma unroll
        for (int p = 0; p < 2; ++p) {
            f4 A = bias[p];
            A = __builtin_amdgcn_mfma_f32_16x16x32_bf16(w1h[p], b1h, A, 0, 0, 0);
            A = __builtin_amdgcn_mfma_f32_16x16x32_bf16(w1h[p], b1l, A, 0, 0, 0);
            A = __builtin_amdgcn_mfma_f32_16x16x32_bf16(w1l[p], b1h, A, 0, 0, 0);
            f4 R = {0.0f, 0.0f, 0.0f, 0.0f};
            R = __builtin_amdgcn_mfma_f32_16x16x32_bf16(w2h[p], b2h, R, 0, 0, 0);
            R = __builtin_amdgcn_mfma_f32_16x16x32_bf16(w2h[p], b2l, R, 0, 0, 0);
            R = __builtin_amdgcn_mfma_f32_16x16x32_bf16(w2l[p], b2h, R, 0, 0, 0);
            f4 s = A + R;
            *(f4*)&gb[nl][32 * gate + 16 * p + 4 * q] = s;
        }
        __syncthreads();

        // ================= phase B: 1 unit per thread =================
        const bool act = ll ? (i >= 1) : (i < T);
        if (act) {
            const float (*gr)[136] = ll ? g1 : g0;
            float gi_ = gr[ln][ 0 + lu];
            float gf_ = gr[ln][32 + lu];
            float gg_ = gr[ln][64 + lu];
            float go_ = gr[ln][96 + lu];
            float iv = sigm(gi_), fv = sigm(gf_);
            float gv = tanh_f(gg_), ov = sigm(go_);
            c = fmaf(fv, c, iv * gv);
            float hv = ov * tanh_f(c);
            short a, b; splitf(hv, a, b);
            if (ll == 0) {
                h0hi[ln][lu] = a; h0lo[ln][lu] = b;
            } else {
                h1hi[ln][lu] = a; h1lo[ln][lu] = b;
                if (i == T) h1f[ln][lu] = hv;     // h1(T-1) for the head
            }
        }
        __syncthreads();
    }

    // ---- output head: out[b0+n] = b_out + W_out . h1(T-1) ----
    if (tid < BT) {
        float acc = b_out[0];
        #pragma unroll
        for (int u = 0; u < H; ++u) acc = fmaf(W_out[u], h1f[tid][u], acc);
        out[b0 + tid] = acc;
    }
}

extern "C" void kernel_launch(void* const* d_in, const int* in_sizes, int n_in,
                              void* d_out, int out_size, void* d_ws, size_t ws_size,
                              hipStream_t stream) {
    const float* x     = (const float*)d_in[0];
    const float* W_ih0 = (const float*)d_in[1];
    const float* W_hh0 = (const float*)d_in[2];
    const float* b_ih0 = (const float*)d_in[3];
    const float* b_hh0 = (const float*)d_in[4];
    const float* W_ih1 = (const float*)d_in[5];
    const float* W_hh1 = (const float*)d_in[6];
    const float* b_ih1 = (const float*)d_in[7];
    const float* b_hh1 = (const float*)d_in[8];
    const float* W_out = (const float*)d_in[9];
    const float* b_out = (const float*)d_in[10];
    float* out = (float*)d_out;

    const int B = out_size;          // 4096
    lstm_8w<<<B / BT, BLK, 0, stream>>>(x, W_ih0, W_hh0, b_ih0, b_hh0,
                                        W_ih1, W_hh1, b_ih1, b_hh1,
                                        W_out, b_out, out);
}

// Round 11
// 449.703 us; speedup vs baseline: 1.3907x; 1.2292x over previous
//
#include <hip/hip_runtime.h>
#include <cmath>

// x [B=4096][T=512][D=4], H=32, gates 4H=128 (PyTorch order i,f,g,o).
constexpr int T   = 512;
constexpr int D   = 4;
constexpr int H   = 32;
constexpr int BT  = 16;    // batch cols per block — ALL real (no junk cols)
constexpr int BLK = 256;   // 4 waves: (layer, unit-half)

typedef short bf8 __attribute__((ext_vector_type(8)));  // 8 bf16 (4 VGPRs)
typedef short s4v __attribute__((ext_vector_type(4)));  // 4 bf16 (8B)
typedef float f4  __attribute__((ext_vector_type(4)));  // MFMA C/D

static __device__ __forceinline__ float sigm(float z) {
    return __builtin_amdgcn_rcpf(1.0f + __expf(-z));
}
static __device__ __forceinline__ float tanh_f(float z) {
    return fmaf(__builtin_amdgcn_rcpf(1.0f + __expf(-2.0f * z)), 2.0f, -1.0f);
}
// fp32 -> bf16 hi (truncate) + bf16 lo (residual): hi+lo ~ 16 mantissa bits
static __device__ __forceinline__ void splitf(float v, short& hi, short& lo) {
    unsigned uv = __float_as_uint(v);
    hi = (short)(uv >> 16);
    float r = v - __uint_as_float(uv & 0xffff0000u);
    lo = (short)(__float_as_uint(r) >> 16);
}

// Grid 256 x 256 threads = 1 block/CU, 1 wave/SIMD — but the leanest
// possible per-iter issue: no junk columns, no junk activations, no gate
// LDS, ONE barrier.
// Wave w = (layer = w>>1, ug = (w&1)*16): computes ALL FOUR gate tiles
// (tile g = gate rows 32g+ug..+15) for its 16 units x 16 batch. After the
// 24 MFMAs each lane holds i,f,g,o of units ug+4q+r, col nl in registers
// -> lane-local state update (4 real updates/lane: the transcendental
// floor). h round-trips LDS only as pre-split bf16 fragments (2 b64
// writes, 2-4 b128 reads per wave-iter), double-buffered.
__global__ __launch_bounds__(BLK, 1) void lstm_lane16(
    const float* __restrict__ x,
    const float* __restrict__ W_ih0, const float* __restrict__ W_hh0,
    const float* __restrict__ b_ih0, const float* __restrict__ b_hh0,
    const float* __restrict__ W_ih1, const float* __restrict__ W_hh1,
    const float* __restrict__ b_ih1, const float* __restrict__ b_hh1,
    const float* __restrict__ W_out, const float* __restrict__ b_out,
    float* __restrict__ out)
{
    // [buf][col][unit], row stride 56 shorts = 112 B (16B-multiple for b128,
    // 28 dwords ≡ 28 mod 32 -> 2-way spread = free)
    __shared__ __align__(16) short h0hi[2][16][56];
    __shared__ __align__(16) short h0lo[2][16][56];
    __shared__ __align__(16) short h1hi[2][16][56];
    __shared__ __align__(16) short h1lo[2][16][56];
    __shared__ __align__(16) float h1f[16][36];     // final h1 fp32 for the head

    const int tid   = threadIdx.x;
    const int w     = tid >> 6;
    const int lane  = tid & 63;
    const int q     = lane >> 4;       // quad
    const int nl    = lane & 15;       // batch col (all real)
    const int layer = w >> 1;          // 0: L1, 1: L2
    const int ug    = (w & 1) << 4;    // unit group offset 0 / 16
    const int b0    = blockIdx.x * BT;

    // zero both h buffers
    for (int idx = tid; idx < 2 * 16 * 56; idx += BLK) {
        (&h0hi[0][0][0])[idx] = 0; (&h0lo[0][0][0])[idx] = 0;
        (&h1hi[0][0][0])[idx] = 0; (&h1lo[0][0][0])[idx] = 0;
    }

    // ---- weights: tile g = gate type. A-frag row = 32g + ug + nl, k = 8q+j.
    // W1 dotted with h0 (L1: W_hh0, L2: W_ih1); W2 with the 2nd operand
    // (L1: W_ih0 vs x, K-padded; L2: W_hh1 vs h1).
    const float* W1 = layer ? W_ih1 : W_hh0;
    bf8 w1h[4], w1l[4], w2h[4], w2l[4];
    f4  bias[4];
    #pragma unroll
    for (int g = 0; g < 4; ++g) {
        const int row = 32 * g + ug + nl;
        #pragma unroll
        for (int j = 0; j < 8; ++j) {
            short a, b;
            splitf(W1[row * H + 8 * q + j], a, b); w1h[g][j] = a; w1l[g][j] = b;
            float v2 = layer ? W_hh1[row * H + 8 * q + j]
                             : ((q == 0 && j < 4) ? W_ih0[row * D + j] : 0.0f);
            splitf(v2, a, b); w2h[g][j] = a; w2l[g][j] = b;
        }
        #pragma unroll
        for (int r = 0; r < 4; ++r) {
            const int gr = 32 * g + ug + 4 * q + r;
            bias[g][r] = layer ? (b_ih1[gr] + b_hh1[gr]) : (b_ih0[gr] + b_hh0[gr]);
        }
    }

    const float4* xp = (const float4*)(x + (size_t)(b0 + nl) * (T * D));
    float4 xcur;
    if (layer == 0) xcur = xp[0];

    float c[4] = {0.0f, 0.0f, 0.0f, 0.0f};   // cell state of the 4 owned units

    __syncthreads();

    #pragma unroll 1
    for (int i = 0; i <= T; ++i) {
        const int rb = i & 1, wb = rb ^ 1;

        // B-fragments
        bf8 b1h = *(const bf8*)&h0hi[rb][nl][8 * q];   // h0(i-1)
        bf8 b1l = *(const bf8*)&h0lo[rb][nl][8 * q];
        bf8 b2h, b2l;
        if (layer == 0) {   // x(i): k<4 = x, rest zero (A cols k>=4 zero too)
            bf8 z = {0,0,0,0,0,0,0,0};
            b2h = z; b2l = z;
            short a, b;
            splitf(xcur.x, a, b); b2h[0] = a; b2l[0] = b;
            splitf(xcur.y, a, b); b2h[1] = a; b2l[1] = b;
            splitf(xcur.z, a, b); b2h[2] = a; b2l[2] = b;
            splitf(xcur.w, a, b); b2h[3] = a; b2l[3] = b;
            xcur = xp[(i + 1 < T) ? (i + 1) : (T - 1)];   // prefetch
        } else {            // h1(i-2)
            b2h = *(const bf8*)&h1hi[rb][nl][8 * q];
            b2l = *(const bf8*)&h1lo[rb][nl][8 * q];
        }

        // ---- 24 MFMAs: 4 gate tiles x (two independent 3-chains) ----
        f4 acc[4];
        #pragma unroll
        for (int g = 0; g < 4; ++g) {
            f4 A = bias[g];
            A = __builtin_amdgcn_mfma_f32_16x16x32_bf16(w1h[g], b1h, A, 0, 0, 0);
            A = __builtin_amdgcn_mfma_f32_16x16x32_bf16(w1h[g], b1l, A, 0, 0, 0);
            A = __builtin_amdgcn_mfma_f32_16x16x32_bf16(w1l[g], b1h, A, 0, 0, 0);
            f4 R = {0.0f, 0.0f, 0.0f, 0.0f};
            R = __builtin_amdgcn_mfma_f32_16x16x32_bf16(w2h[g], b2h, R, 0, 0, 0);
            R = __builtin_amdgcn_mfma_f32_16x16x32_bf16(w2h[g], b2l, R, 0, 0, 0);
            R = __builtin_amdgcn_mfma_f32_16x16x32_bf16(w2l[g], b2h, R, 0, 0, 0);
            acc[g] = A + R;
        }

        // ---- lane-local state update: units ug+4q+r, col nl (all real) ----
        const bool act = layer ? (i >= 1) : (i < T);
        if (act) {
            s4v hh, hl;
            float hv[4];
            #pragma unroll
            for (int r = 0; r < 4; ++r) {
                float iv = sigm(acc[0][r]);
                float fv = sigm(acc[1][r]);
                float gv = tanh_f(acc[2][r]);
                float ov = sigm(acc[3][r]);
                c[r] = fmaf(fv, c[r], iv * gv);
                hv[r] = ov * tanh_f(c[r]);
                short a, b; splitf(hv[r], a, b); hh[r] = a; hl[r] = b;
            }
            if (layer == 0) {
                *(s4v*)&h0hi[wb][nl][ug + 4 * q] = hh;
                *(s4v*)&h0lo[wb][nl][ug + 4 * q] = hl;
            } else {
                *(s4v*)&h1hi[wb][nl][ug + 4 * q] = hh;
                *(s4v*)&h1lo[wb][nl][ug + 4 * q] = hl;
                if (i == T) {   // h1(T-1) for the output head
                    float4 hw; hw.x = hv[0]; hw.y = hv[1]; hw.z = hv[2]; hw.w = hv[3];
                    *(float4*)&h1f[nl][ug + 4 * q] = hw;
                }
            }
        }
        __syncthreads();   // single barrier: buffer wb becomes rb of iter i+1
    }

    // ---- output head: out[b0+n] = b_out + W_out . h1(T-1) ----
    if (tid < BT) {
        float acc = b_out[0];
        #pragma unroll
        for (int u = 0; u < H; ++u) acc = fmaf(W_out[u], h1f[tid][u], acc);
        out[b0 + tid] = acc;
    }
}

extern "C" void kernel_launch(void* const* d_in, const int* in_sizes, int n_in,
                              void* d_out, int out_size, void* d_ws, size_t ws_size,
                              hipStream_t stream) {
    const float* x     = (const float*)d_in[0];
    const float* W_ih0 = (const float*)d_in[1];
    const float* W_hh0 = (const float*)d_in[2];
    const float* b_ih0 = (const float*)d_in[3];
    const float* b_hh0 = (const float*)d_in[4];
    const float* W_ih1 = (const float*)d_in[5];
    const float* W_hh1 = (const float*)d_in[6];
    const float* b_ih1 = (const float*)d_in[7];
    const float* b_hh1 = (const float*)d_in[8];
    const float* W_out = (const float*)d_in[9];
    const float* b_out = (const float*)d_in[10];
    float* out = (float*)d_out;

    const int B = out_size;          // 4096
    lstm_lane16<<<B / BT, BLK, 0, stream>>>(x, W_ih0, W_hh0, b_ih0, b_hh0,
                                            W_ih1, W_hh1, b_ih1, b_hh1,
                                            W_out, b_out, out);
}